// Round 5
// baseline (2451.944 us; speedup 1.0000x reference)
//
#include <hip/hip_runtime.h>
#include <math.h>

#define Ee   200
#define Hh   128
#define G4   512          // 4*H
#define Kk   24
#define Bb   64
#define Tt   1024
#define HIDd 256
#define NEGf (-10000.0f)
#define PSTR 9            // partial-sum LDS stride (odd -> conflict-free)
#define POLL_LIMIT (1 << 21)

// ---------------------------------------------------------------------------
// K0: Wt[k][n] (k<200, n<1024): n<512 -> W_ih_f[n][k], else W_ih_b[n-512][k]
//     blocks 0..3 also zero the 1024 ready-flags (fresh every launch).
// ---------------------------------------------------------------------------
__global__ __launch_bounds__(256) void k_wt(const float* __restrict__ Wf,
                                            const float* __restrict__ Wb,
                                            float* __restrict__ Wt,
                                            int* __restrict__ flags) {
    int idx = blockIdx.x * 256 + threadIdx.x;
    if (blockIdx.x < 4) flags[idx] = 0;
    if (idx >= Ee * 1024) return;
    int k = idx >> 10, n = idx & 1023;
    Wt[idx] = (n < G4) ? Wf[n * Ee + k] : Wb[(n - G4) * Ee + k];
}

// ---------------------------------------------------------------------------
// consumer: v2 k_lstm2 (proven 920us, conflict-free) + optional flag polling.
//   smem carve: hsh[128] | gsh[512] | ps[(512+24)*9]  = 5464 floats
// ---------------------------------------------------------------------------
__device__ __forceinline__ void lstm_consumer(
        const float* __restrict__ Uc, const float* __restrict__ Whh,
        const float* __restrict__ bih, const float* __restrict__ bhh,
        const float* __restrict__ h0v, const float* __restrict__ c0v,
        const float* __restrict__ Wout,
        float* __restrict__ hst, float* __restrict__ cst,
        float* __restrict__ pf, int* flags,
        int b, int d, int c0T, int CT, int first, int unified, float* smem) {
    float* hsh = smem;            // 128
    float* gsh = smem + 128;      // 512
    float* ps  = smem + 640;      // 4824

    int tid  = threadIdx.x;
    int lane = tid & 63, wv = tid >> 6;

    float bias = bih[tid] + bhh[tid];

    float w[8][16];
#pragma unroll
    for (int ri = 0; ri < 8; ++ri) {
        const float* wr = Whh + (size_t)(ri * 64 + lane) * Hh + wv * 16;
#pragma unroll
        for (int c4 = 0; c4 < 4; ++c4)
            *(float4*)&w[ri][c4 * 4] = *(const float4*)(wr + c4 * 4);
    }
    float wt[16];
    if (lane < Kk) {
        const float* wr = Wout + (size_t)lane * HIDd + d * Hh + wv * 16;
#pragma unroll
        for (int c4 = 0; c4 < 4; ++c4)
            *(float4*)&wt[c4 * 4] = *(const float4*)(wr + c4 * 4);
    }

    float cc = 0.f;
    if (tid < Hh) {
        int si = (d * Bb + b) * Hh + tid;
        hsh[tid] = first ? h0v[si] : hst[si];
        cc       = first ? c0v[si] : cst[si];
    }

    // prologue poll: global t for steps 0..8 must be produced
    if (flags) {
        if (tid < 5) {
            int s_hi = 8 < CT - 1 ? 8 : CT - 1;
            int t_a  = d ? (Tt - 1 - s_hi) : 0;
            int t_b  = d ? (Tt - 1) : s_hi;
            int mt   = (t_a >> 1) + tid;
            int mtm  = t_b >> 1;
            if (mt > mtm) mt = mtm;
            int* fp = flags + d * 512 + mt;
            int cnt = 0;
            while (__hip_atomic_load(fp, __ATOMIC_RELAXED,
                                     __HIP_MEMORY_SCOPE_AGENT) < 2) {
                __builtin_amdgcn_s_sleep(8);
                if (++cnt > POLL_LIMIT) break;
            }
            __threadfence();
        }
    }
    __syncthreads();

    const float* Ub = Uc + (size_t)d * ((size_t)CT * Bb * G4);
    int u0 = unified ? (d ? (Tt - 1) : 0) : 0;
    int us = unified ? (d ? -1 : 1) : 1;

    float ucur = Ub[(size_t)u0 * (Bb * G4) + b * G4 + tid];
    float unext = 0.f;

    for (int i = 0; i <= CT; ++i) {
        int last = (i == CT);
        // ---- P1: partial dots off current hsh = h(i-1) ----
        float hv[16];
        *(float4*)&hv[0]  = *(const float4*)&hsh[wv * 16];
        *(float4*)&hv[4]  = *(const float4*)&hsh[wv * 16 + 4];
        *(float4*)&hv[8]  = *(const float4*)&hsh[wv * 16 + 8];
        *(float4*)&hv[12] = *(const float4*)&hsh[wv * 16 + 12];

        if (lane < Kk) {
            float s = 0.f;
#pragma unroll
            for (int c = 0; c < 16; ++c) s = fmaf(wt[c], hv[c], s);
            ps[(G4 + lane) * PSTR + wv] = s;
        }
        if (!last) {
#pragma unroll
            for (int ri = 0; ri < 8; ++ri) {
                float s = 0.f;
#pragma unroll
                for (int c = 0; c < 16; ++c) s = fmaf(w[ri][c], hv[c], s);
                ps[(ri * 64 + lane) * PSTR + wv] = s;
            }
            if (i + 1 < CT)
                unext = Ub[(size_t)(u0 + (i + 1) * us) * (Bb * G4) + b * G4 + tid];
        }
        __syncthreads();

        // ---- P2: reduce + activate ----
        if (!last) {
            const float* pr = ps + (size_t)tid * PSTR;
            float s = ((pr[0] + pr[1]) + (pr[2] + pr[3])) +
                      ((pr[4] + pr[5]) + (pr[6] + pr[7]));
            s += ucur + bias;
            int gt = tid >> 7;
            gsh[tid] = (gt == 2) ? tanhf(s) : 1.f / (1.f + expf(-s));
        }
        __syncthreads();

        // ---- P3: cell + tag emit of h(i-1) + (poll window, idle wave) ----
        if (!last && tid < Hh) {
            float gi = gsh[tid], gf = gsh[Hh + tid];
            float gg = gsh[2 * Hh + tid], go = gsh[3 * Hh + tid];
            cc = gf * cc + gi * gg;
            hsh[tid] = go * tanhf(cc);
        }
        if (tid >= 128 && tid < 128 + Kk && i >= 1) {
            int k = tid - 128;
            const float* pr = ps + (size_t)(G4 + k) * PSTR;
            float s = ((pr[0] + pr[1]) + (pr[2] + pr[3])) +
                      ((pr[4] + pr[5]) + (pr[6] + pr[7]));
            int tp = c0T + i - 1;
            int tg = d ? (Tt - 1 - tp) : tp;
            pf[((size_t)(d * Bb + b) * Tt + tg) * Kk + k] = s;
        }
        if (flags && (i & 7) == 7 && i + 2 <= CT - 1 &&
            tid >= 192 && tid < 197) {
            int j = tid - 192;
            int s_lo = i + 2;
            int s_hi = i + 9 < CT - 1 ? i + 9 : CT - 1;
            int t_a  = d ? (Tt - 1 - s_hi) : s_lo;
            int t_b  = d ? (Tt - 1 - s_lo) : s_hi;
            int mt   = (t_a >> 1) + j;
            int mtm  = t_b >> 1;
            if (mt > mtm) mt = mtm;
            int* fp = flags + d * 512 + mt;
            int cnt = 0;
            while (__hip_atomic_load(fp, __ATOMIC_RELAXED,
                                     __HIP_MEMORY_SCOPE_AGENT) < 2) {
                __builtin_amdgcn_s_sleep(8);
                if (++cnt > POLL_LIMIT) break;
            }
            __threadfence();
        }
        __syncthreads();
        ucur = unext;
    }

    if (tid < Hh) {
        int si = (d * Bb + b) * Hh + tid;
        hst[si] = hsh[tid];
        cst[si] = cc;
    }
}

// ---------------------------------------------------------------------------
// producer: 16 GEMM tiles (BM=128 x BN=256, K=200) per block, 512 threads.
//   Tile order interleaves front (m ascending, feeds d=0) and back
//   (m descending, feeds d=1). After each tile: fence + flag atomicAdd.
//   smem carve: As[8][128] | Bs[8][256] | toks[128]
// ---------------------------------------------------------------------------
__device__ __forceinline__ void gemm_producer(
        const int* __restrict__ sent, const float* __restrict__ emb,
        const float* __restrict__ Wt, float* __restrict__ Uc,
        int* __restrict__ flags, int p, float* smem) {
    float* As = smem;                  // [8][128]
    float* Bs = smem + 1024;           // [8][256]
    int*   toks = (int*)(smem + 3072); // [128]

    int tid = threadIdx.x;
    int ty2 = tid >> 5, tx2 = tid & 31;
    int am = tid & 127, ak4 = (tid >> 7) & 1;
    int brow = tid >> 6, bc4 = tid & 63;

    for (int s = 0; s < 16; ++s) {
        int q = s * 128 + p;
        int mt, nt;
        if ((q & 1) == 0) { int f = q >> 1; mt = f >> 2; nt = f & 3; }
        else             { int bk = q >> 1; mt = 511 - (bk >> 2); nt = bk & 3; }
        int m0 = mt * 128, n0 = nt * 256;

        __syncthreads();
        if (tid < 128) {
            int m = m0 + tid;
            toks[tid] = sent[(m & 63) * Tt + (m >> 6)];
        }
        __syncthreads();

        const float* aptr = emb + (size_t)toks[am] * Ee + ak4 * 4;
        const float* bptr = Wt + (size_t)brow * 1024 + n0 + bc4 * 4;

        float acc[8][8];
#pragma unroll
        for (int i = 0; i < 8; ++i)
#pragma unroll
            for (int j = 0; j < 8; ++j) acc[i][j] = 0.f;

        float4 av = make_float4(0, 0, 0, 0), bv;
        if (tid < 256) av = *(const float4*)(aptr);
        bv = *(const float4*)(bptr);

        for (int kc = 0; kc < Ee; kc += 8) {
            if (tid < 256) {
                As[(ak4 * 4 + 0) * 128 + am] = av.x;
                As[(ak4 * 4 + 1) * 128 + am] = av.y;
                As[(ak4 * 4 + 2) * 128 + am] = av.z;
                As[(ak4 * 4 + 3) * 128 + am] = av.w;
            }
            *(float4*)&Bs[brow * 256 + bc4 * 4] = bv;
            __syncthreads();

            if (kc + 8 < Ee) {
                if (tid < 256) av = *(const float4*)(aptr + kc + 8);
                bv = *(const float4*)(bptr + (size_t)(kc + 8) * 1024);
            }

#pragma unroll
            for (int k = 0; k < 8; ++k) {
                float a_[8], b_[8];
                *(float4*)&a_[0] = *(const float4*)&As[k * 128 + ty2 * 8];
                *(float4*)&a_[4] = *(const float4*)&As[k * 128 + ty2 * 8 + 4];
                *(float4*)&b_[0] = *(const float4*)&Bs[k * 256 + tx2 * 4];
                *(float4*)&b_[4] = *(const float4*)&Bs[k * 256 + tx2 * 4 + 128];
#pragma unroll
                for (int i = 0; i < 8; ++i)
#pragma unroll
                    for (int j = 0; j < 8; ++j)
                        acc[i][j] = fmaf(a_[i], b_[j], acc[i][j]);
            }
            __syncthreads();
        }

        int dd = nt >> 1, ncol = (nt & 1) * 256;
        float* base = Uc + (size_t)dd * ((size_t)Tt * Bb * G4);
#pragma unroll
        for (int i = 0; i < 8; ++i) {
            float* dst = base + (size_t)(m0 + ty2 * 8 + i) * G4 + ncol + tx2 * 4;
            *(float4*)dst = make_float4(acc[i][0], acc[i][1], acc[i][2], acc[i][3]);
            *(float4*)(dst + 128) = make_float4(acc[i][4], acc[i][5],
                                                acc[i][6], acc[i][7]);
        }
        __threadfence();
        __syncthreads();
        if (tid == 0) atomicAdd(&flags[dd * 512 + mt], 1);
    }
}

// ---------------------------------------------------------------------------
// fused producer/consumer kernel: blocks 0..127 = GEMM producers,
// blocks 128..255 = LSTM consumers. 256 blocks <= 256 CUs -> co-resident.
// ---------------------------------------------------------------------------
__global__ __launch_bounds__(512) void k_fused(const int* __restrict__ sent,
                                               const float* __restrict__ emb,
                                               const float* __restrict__ Wt,
                                               float* __restrict__ Uc,
                                               const float* __restrict__ Whh_f,
                                               const float* __restrict__ Whh_b,
                                               const float* __restrict__ bih_f,
                                               const float* __restrict__ bhh_f,
                                               const float* __restrict__ bih_b,
                                               const float* __restrict__ bhh_b,
                                               const float* __restrict__ h0,
                                               const float* __restrict__ c0,
                                               const float* __restrict__ Wout,
                                               float* __restrict__ hst,
                                               float* __restrict__ cst,
                                               float* __restrict__ pf,
                                               int* __restrict__ flags) {
    __shared__ float smem[5464];
    int bi = blockIdx.x;
    if (bi < 128) {
        gemm_producer(sent, emb, Wt, Uc, flags, bi, smem);
    } else {
        int cb = bi - 128;
        int d = cb >> 6, b = cb & 63;
        lstm_consumer(Uc, d ? Whh_b : Whh_f, d ? bih_b : bih_f,
                      d ? bhh_b : bhh_f, h0, c0, Wout, hst, cst, pf,
                      flags, b, d, 0, Tt, 1, 1, smem);
    }
}

// ---------------------------------------------------------------------------
// fallback (small ws): chunked gemm (256 thr) + solo lstm, sequential.
// ---------------------------------------------------------------------------
__global__ __launch_bounds__(256, 2) void k_gemm2(const int* __restrict__ sent,
                                                  const float* __restrict__ emb,
                                                  const float* __restrict__ Wt,
                                                  float* __restrict__ Uc,
                                                  int c0T, int CT) {
    __shared__ float As[8][128];
    __shared__ float Bs[8][256];
    __shared__ int   toks[128];

    int tid = threadIdx.x;
    int n0  = blockIdx.x * 256;
    int m0  = blockIdx.y * 128;
    int dz  = blockIdx.z;
    int ty  = tid >> 4, tx = tid & 15;

    if (tid < 128) {
        int m = m0 + tid;
        int it = m >> 6, b = m & 63;
        int t = dz ? (Tt - 1 - (c0T + it)) : (c0T + it);
        toks[tid] = sent[b * Tt + t];
    }
    __syncthreads();

    int am = tid & 127, ak4 = tid >> 7;
    int brow = tid >> 5, bc4 = tid & 31;

    const float* aptr = emb + (size_t)toks[am] * Ee + ak4 * 4;
    const float* bptr = Wt + (size_t)brow * 1024 + dz * G4 + n0 + bc4 * 4;

    float acc[8][16];
#pragma unroll
    for (int i = 0; i < 8; ++i)
#pragma unroll
        for (int j = 0; j < 16; ++j) acc[i][j] = 0.f;

    for (int kc = 0; kc < Ee; kc += 8) {
        float4 av  = *(const float4*)(aptr + kc);
        float4 bv0 = *(const float4*)(bptr + (size_t)kc * 1024);
        float4 bv1 = *(const float4*)(bptr + (size_t)kc * 1024 + 128);
        As[ak4 * 4 + 0][am] = av.x;
        As[ak4 * 4 + 1][am] = av.y;
        As[ak4 * 4 + 2][am] = av.z;
        As[ak4 * 4 + 3][am] = av.w;
        *(float4*)&Bs[brow][bc4 * 4]       = bv0;
        *(float4*)&Bs[brow][128 + bc4 * 4] = bv1;
        __syncthreads();
#pragma unroll
        for (int k = 0; k < 8; ++k) {
            float a_[8], b_[16];
            *(float4*)&a_[0] = *(const float4*)&As[k][ty * 8];
            *(float4*)&a_[4] = *(const float4*)&As[k][ty * 8 + 4];
#pragma unroll
            for (int q = 0; q < 4; ++q)
                *(float4*)&b_[4 * q] = *(const float4*)&Bs[k][tx * 4 + 64 * q];
#pragma unroll
            for (int i = 0; i < 8; ++i)
#pragma unroll
                for (int j = 0; j < 16; ++j)
                    acc[i][j] = fmaf(a_[i], b_[j], acc[i][j]);
        }
        __syncthreads();
    }

    float* base = Uc + (size_t)dz * ((size_t)CT * Bb * G4);
#pragma unroll
    for (int i = 0; i < 8; ++i) {
        float* dst = base + (size_t)(m0 + ty * 8 + i) * G4 + n0 + tx * 4;
#pragma unroll
        for (int q = 0; q < 4; ++q)
            *(float4*)(dst + 64 * q) = make_float4(acc[i][4 * q], acc[i][4 * q + 1],
                                                   acc[i][4 * q + 2], acc[i][4 * q + 3]);
    }
}

__global__ __launch_bounds__(512) void k_lstm_solo(const float* __restrict__ Uc,
                                                   const float* __restrict__ Whh_f,
                                                   const float* __restrict__ Whh_b,
                                                   const float* __restrict__ bih_f,
                                                   const float* __restrict__ bhh_f,
                                                   const float* __restrict__ bih_b,
                                                   const float* __restrict__ bhh_b,
                                                   const float* __restrict__ h0,
                                                   const float* __restrict__ c0,
                                                   const float* __restrict__ Wout,
                                                   float* __restrict__ hst,
                                                   float* __restrict__ cst,
                                                   float* __restrict__ pf,
                                                   int c0T, int CT, int first) {
    __shared__ float smem[5464];
    int b = blockIdx.x & 63, d = blockIdx.x >> 6;
    lstm_consumer(Uc, d ? Whh_b : Whh_f, d ? bih_b : bih_f, d ? bhh_b : bhh_f,
                  h0, c0, Wout, hst, cst, pf, nullptr, b, d,
                  c0T, CT, first, 0, smem);
}

// ---------------------------------------------------------------------------
// K3: Viterbi. 1 wave per b; v in lane regs; feat prefetch one step ahead.
// ---------------------------------------------------------------------------
__global__ __launch_bounds__(64) void k_viterbi(const float* __restrict__ pf,
                                                const float* __restrict__ bout,
                                                const float* __restrict__ trans,
                                                float* __restrict__ out) {
    __shared__ unsigned char bptr[Tt * Kk];
    __shared__ float tsh[Kk];
    __shared__ unsigned char path[Tt];

    int lane = threadIdx.x;
    int b    = blockIdx.x;
    int half   = (lane >= Kk) ? 1 : 0;
    int n      = half ? (lane - Kk) : lane;
    int active = (lane < 2 * Kk);

    float tr[12];
    float bo = 0.f;
    if (active) {
#pragma unroll
        for (int j = 0; j < 12; ++j) tr[j] = trans[n * Kk + half * 12 + j];
        bo = bout[n];
    }
    float v = (active && half == 0 && n == 0) ? 0.f : NEGf;   // START=0

    const float* p0 = pf + (size_t)b * Tt * Kk;
    const float* p1 = pf + (size_t)(Bb + b) * Tt * Kk;

    float pre = (active && half == 0) ? (p0[n] + p1[n]) : 0.f;

    for (int t = 0; t < Tt; ++t) {
        float pren = 0.f;
        if (t + 1 < Tt && active && half == 0)
            pren = p0[(t + 1) * Kk + n] + p1[(t + 1) * Kk + n];

        float best = NEGf;
        int   bp   = 0;
        if (active) {
            int pb = half * 12;
            best = __shfl(v, pb) + tr[0];
            bp   = pb;
#pragma unroll
            for (int j = 1; j < 12; ++j) {
                float s = __shfl(v, pb + j) + tr[j];
                if (s > best) { best = s; bp = pb + j; }   // strict >: first-max
            }
        }
        float ob  = __shfl(best, n + Kk);
        int   obp = __shfl(bp,   n + Kk);
        if (active && half == 0) {
            if (ob > best) { best = ob; bp = obp; }        // tie -> lower half
            v = best + pre + bo;
            bptr[t * Kk + n] = (unsigned char)bp;
        }
        pre = pren;
    }

    if (half == 0 && lane < Kk) tsh[n] = v + trans[1 * Kk + n];   // STOP=1
    __syncthreads();

    if (lane == 0) {
        float bestv = tsh[0];
        int tag = 0;
        for (int q = 1; q < Kk; ++q)
            if (tsh[q] > bestv) { bestv = tsh[q]; tag = q; }
        out[b] = bestv;
        for (int t = Tt - 1; t >= 1; --t) {
            path[t] = (unsigned char)tag;
            tag = bptr[t * Kk + tag];
        }
        path[0] = (unsigned char)tag;
    }
    __syncthreads();

    float* otag = out + Bb + (size_t)b * Tt;
    for (int t = lane; t < Tt; t += 64) otag[t] = (float)path[t];
}

// ---------------------------------------------------------------------------
// host launcher
//   ws floats: Wt 204800 | pf 3145728 | hst 16384 | cst 16384 | flags 1024(int)
//              | Uc (2*Tt*64*512 unified, else 2*CT*64*512)
// ---------------------------------------------------------------------------
extern "C" void kernel_launch(void* const* d_in, const int* in_sizes, int n_in,
                              void* d_out, int out_size, void* d_ws, size_t ws_size,
                              hipStream_t stream) {
    const int*   sent  = (const int*)d_in[0];
    const float* emb   = (const float*)d_in[2];
    const float* Wih_f = (const float*)d_in[3];
    const float* Whh_f = (const float*)d_in[4];
    const float* bih_f = (const float*)d_in[5];
    const float* bhh_f = (const float*)d_in[6];
    const float* Wih_b = (const float*)d_in[7];
    const float* Whh_b = (const float*)d_in[8];
    const float* bih_b = (const float*)d_in[9];
    const float* bhh_b = (const float*)d_in[10];
    const float* h0    = (const float*)d_in[11];
    const float* c0    = (const float*)d_in[12];
    const float* Wout  = (const float*)d_in[13];
    const float* bout  = (const float*)d_in[14];
    const float* trans = (const float*)d_in[15];

    float* ws    = (float*)d_ws;
    float* Wt    = ws;
    float* pf    = Wt + 204800;
    float* hst   = pf + 3145728;
    float* cst   = hst + 16384;
    int*   flags = (int*)(cst + 16384);
    float* Uc    = cst + 16384 + 1024;

    const size_t fixedf = 204800 + 3145728 + 16384 + 16384 + 1024;
    size_t needU = (size_t)2 * Tt * Bb * G4;
    int unified = ((fixedf + needU) * 4 <= ws_size);

    k_wt<<<(Ee * 1024 + 255) / 256, 256, 0, stream>>>(Wih_f, Wih_b, Wt, flags);

    if (unified) {
        k_fused<<<256, 512, 0, stream>>>(sent, emb, Wt, Uc,
                                         Whh_f, Whh_b, bih_f, bhh_f,
                                         bih_b, bhh_b, h0, c0, Wout,
                                         hst, cst, pf, flags);
    } else {
        int CT = 64;
        const int cands[3] = {512, 256, 128};
        for (int ci = 0; ci < 3; ++ci)
            if ((fixedf + (size_t)2 * cands[ci] * Bb * G4) * 4 <= ws_size) {
                CT = cands[ci]; break;
            }
        int NC = Tt / CT;
        for (int cix = 0; cix < NC; ++cix) {
            k_gemm2<<<dim3(2, CT * 64 / 128, 2), 256, 0, stream>>>(
                sent, emb, Wt, Uc, cix * CT, CT);
            k_lstm_solo<<<128, 512, 0, stream>>>(Uc, Whh_f, Whh_b, bih_f, bhh_f,
                                                 bih_b, bhh_b, h0, c0, Wout,
                                                 hst, cst, pf, cix * CT, CT,
                                                 cix == 0);
        }
    }

    k_viterbi<<<Bb, 64, 0, stream>>>(pf, bout, trans, (float*)d_out);
}

// Round 7
// 2234.671 us; speedup vs baseline: 1.0972x; 1.0972x over previous
//
#include <hip/hip_runtime.h>
#include <math.h>

#define Ee   200
#define Hh   128
#define G4   512          // 4*H
#define Kk   24
#define Bb   64
#define Tt   1024
#define HIDd 256
#define NEGf (-10000.0f)
#define PSTR 9            // partial-sum LDS stride (odd -> conflict-free)
#define POLL_LIMIT (1 << 21)

// ---------------------------------------------------------------------------
// K0: Wt[k][n] (k<200, n<1024): n<512 -> W_ih_f[n][k], else W_ih_b[n-512][k]
//     blocks 0..3 also zero the 1024 ready-flags (fresh every launch).
// ---------------------------------------------------------------------------
__global__ __launch_bounds__(256) void k_wt(const float* __restrict__ Wf,
                                            const float* __restrict__ Wb,
                                            float* __restrict__ Wt,
                                            int* __restrict__ flags) {
    int idx = blockIdx.x * 256 + threadIdx.x;
    if (blockIdx.x < 4) flags[idx] = 0;
    if (idx >= Ee * 1024) return;
    int k = idx >> 10, n = idx & 1023;
    Wt[idx] = (n < G4) ? Wf[n * Ee + k] : Wb[(n - G4) * Ee + k];
}

// ---------------------------------------------------------------------------
// consumer: v2 LSTM (conflict-free) + 2-deep U prefetch + flag polling.
//   smem carve: hsh[128] | gsh[512] | ps[(512+24)*9]  = 5464 floats
// ---------------------------------------------------------------------------
__device__ __forceinline__ void lstm_consumer(
        const float* __restrict__ Uc, const float* __restrict__ Whh,
        const float* __restrict__ bih, const float* __restrict__ bhh,
        const float* __restrict__ h0v, const float* __restrict__ c0v,
        const float* __restrict__ Wout,
        float* __restrict__ hst, float* __restrict__ cst,
        float* __restrict__ pf, int* flags,
        int b, int d, int c0T, int CT, int first, int unified, float* smem) {
    float* hsh = smem;            // 128
    float* gsh = smem + 128;      // 512
    float* ps  = smem + 640;      // 4824

    int tid  = threadIdx.x;
    int lane = tid & 63, wv = tid >> 6;

    float bias = bih[tid] + bhh[tid];

    float w[8][16];
#pragma unroll
    for (int ri = 0; ri < 8; ++ri) {
        const float* wr = Whh + (size_t)(ri * 64 + lane) * Hh + wv * 16;
#pragma unroll
        for (int c4 = 0; c4 < 4; ++c4)
            *(float4*)&w[ri][c4 * 4] = *(const float4*)(wr + c4 * 4);
    }
    float wt[16];
    if (lane < Kk) {
        const float* wr = Wout + (size_t)lane * HIDd + d * Hh + wv * 16;
#pragma unroll
        for (int c4 = 0; c4 < 4; ++c4)
            *(float4*)&wt[c4 * 4] = *(const float4*)(wr + c4 * 4);
    }

    float cc = 0.f;
    if (tid < Hh) {
        int si = (d * Bb + b) * Hh + tid;
        hsh[tid] = first ? h0v[si] : hst[si];
        cc       = first ? c0v[si] : cst[si];
    }

    // prologue poll: steps 0..9 of this direction must be produced
    if (flags) {
        if (tid < 6) {
            int s_hi = 9 < CT - 1 ? 9 : CT - 1;
            int t_a  = d ? (Tt - 1 - s_hi) : 0;
            int t_b  = d ? (Tt - 1) : s_hi;
            int mt   = (t_a >> 1) + tid;
            int mtm  = t_b >> 1;
            if (mt > mtm) mt = mtm;
            int* fp = flags + d * 512 + mt;
            int cnt = 0;
            while (__hip_atomic_load(fp, __ATOMIC_RELAXED,
                                     __HIP_MEMORY_SCOPE_AGENT) < 2) {
                __builtin_amdgcn_s_sleep(8);
                if (++cnt > POLL_LIMIT) break;
            }
            __threadfence();
        }
    }
    __syncthreads();

    const float* Ub = Uc + (size_t)d * ((size_t)CT * Bb * G4);
    int u0 = unified ? (d ? (Tt - 1) : 0) : 0;
    int us = unified ? (d ? -1 : 1) : 1;

    float ucur  = Ub[(size_t)u0 * (Bb * G4) + b * G4 + tid];
    float unext = (CT > 1) ? Ub[(size_t)(u0 + us) * (Bb * G4) + b * G4 + tid] : 0.f;

    for (int i = 0; i <= CT; ++i) {
        int last = (i == CT);
        float unn = 0.f;
        // ---- P1: partial dots off current hsh = h(i-1) ----
        float hv[16];
        *(float4*)&hv[0]  = *(const float4*)&hsh[wv * 16];
        *(float4*)&hv[4]  = *(const float4*)&hsh[wv * 16 + 4];
        *(float4*)&hv[8]  = *(const float4*)&hsh[wv * 16 + 8];
        *(float4*)&hv[12] = *(const float4*)&hsh[wv * 16 + 12];

        if (lane < Kk) {
            float s = 0.f;
#pragma unroll
            for (int c = 0; c < 16; ++c) s = fmaf(wt[c], hv[c], s);
            ps[(G4 + lane) * PSTR + wv] = s;
        }
        if (!last) {
#pragma unroll
            for (int ri = 0; ri < 8; ++ri) {
                float s = 0.f;
#pragma unroll
                for (int c = 0; c < 16; ++c) s = fmaf(w[ri][c], hv[c], s);
                ps[(ri * 64 + lane) * PSTR + wv] = s;
            }
        }
        __syncthreads();

        // ---- P2: 2-ahead U load + reduce + activate ----
        if (!last) {
            if (i + 2 < CT)
                unn = Ub[(size_t)(u0 + (i + 2) * us) * (Bb * G4) + b * G4 + tid];
            const float* pr = ps + (size_t)tid * PSTR;
            float s = ((pr[0] + pr[1]) + (pr[2] + pr[3])) +
                      ((pr[4] + pr[5]) + (pr[6] + pr[7]));
            s += ucur + bias;
            int gt = tid >> 7;
            gsh[tid] = (gt == 2) ? tanhf(s) : 1.f / (1.f + expf(-s));
        }
        __syncthreads();

        // ---- P3: cell + tag emit of h(i-1) + (poll window, idle wave) ----
        if (!last && tid < Hh) {
            float gi = gsh[tid], gf = gsh[Hh + tid];
            float gg = gsh[2 * Hh + tid], go = gsh[3 * Hh + tid];
            cc = gf * cc + gi * gg;
            hsh[tid] = go * tanhf(cc);
        }
        if (tid >= 128 && tid < 128 + Kk && i >= 1) {
            int k = tid - 128;
            const float* pr = ps + (size_t)(G4 + k) * PSTR;
            float s = ((pr[0] + pr[1]) + (pr[2] + pr[3])) +
                      ((pr[4] + pr[5]) + (pr[6] + pr[7]));
            int tp = c0T + i - 1;
            int tg = d ? (Tt - 1 - tp) : tp;
            pf[((size_t)(d * Bb + b) * Tt + tg) * Kk + k] = s;
        }
        if (flags && (i & 7) == 7 && i + 3 <= CT - 1 &&
            tid >= 192 && tid < 197) {
            int j = tid - 192;
            int s_lo = i + 3;
            int s_hi = i + 10 < CT - 1 ? i + 10 : CT - 1;
            int t_a  = d ? (Tt - 1 - s_hi) : s_lo;
            int t_b  = d ? (Tt - 1 - s_lo) : s_hi;
            int mt   = (t_a >> 1) + j;
            int mtm  = t_b >> 1;
            if (mt > mtm) mt = mtm;
            int* fp = flags + d * 512 + mt;
            int cnt = 0;
            while (__hip_atomic_load(fp, __ATOMIC_RELAXED,
                                     __HIP_MEMORY_SCOPE_AGENT) < 2) {
                __builtin_amdgcn_s_sleep(8);
                if (++cnt > POLL_LIMIT) break;
            }
            __threadfence();
        }
        __syncthreads();
        ucur = unext;
        unext = unn;
    }

    if (tid < Hh) {
        int si = (d * Bb + b) * Hh + tid;
        hst[si] = hsh[tid];
        cst[si] = cc;
    }
}

// ---------------------------------------------------------------------------
// producer: 16 GEMM tiles (BM=128 x BN=256, K=200) per block, 512 threads.
// ---------------------------------------------------------------------------
__device__ __forceinline__ void gemm_producer(
        const int* __restrict__ sent, const float* __restrict__ emb,
        const float* __restrict__ Wt, float* __restrict__ Uc,
        int* __restrict__ flags, int p, float* smem) {
    float* As = smem;                  // [8][128]
    float* Bs = smem + 1024;           // [8][256]
    int*   toks = (int*)(smem + 3072); // [128]

    int tid = threadIdx.x;
    int ty2 = tid >> 5, tx2 = tid & 31;
    int am = tid & 127, ak4 = (tid >> 7) & 1;
    int brow = tid >> 6, bc4 = tid & 63;

    for (int s = 0; s < 16; ++s) {
        int q = s * 128 + p;
        int mt, nt;
        if ((q & 1) == 0) { int f = q >> 1; mt = f >> 2; nt = f & 3; }
        else             { int bk = q >> 1; mt = 511 - (bk >> 2); nt = bk & 3; }
        int m0 = mt * 128, n0 = nt * 256;

        __syncthreads();
        if (tid < 128) {
            int m = m0 + tid;
            toks[tid] = sent[(m & 63) * Tt + (m >> 6)];
        }
        __syncthreads();

        const float* aptr = emb + (size_t)toks[am] * Ee + ak4 * 4;
        const float* bptr = Wt + (size_t)brow * 1024 + n0 + bc4 * 4;

        float acc[8][8];
#pragma unroll
        for (int i = 0; i < 8; ++i)
#pragma unroll
            for (int j = 0; j < 8; ++j) acc[i][j] = 0.f;

        float4 av = make_float4(0, 0, 0, 0), bv;
        if (tid < 256) av = *(const float4*)(aptr);
        bv = *(const float4*)(bptr);

        for (int kc = 0; kc < Ee; kc += 8) {
            if (tid < 256) {
                As[(ak4 * 4 + 0) * 128 + am] = av.x;
                As[(ak4 * 4 + 1) * 128 + am] = av.y;
                As[(ak4 * 4 + 2) * 128 + am] = av.z;
                As[(ak4 * 4 + 3) * 128 + am] = av.w;
            }
            *(float4*)&Bs[brow * 256 + bc4 * 4] = bv;
            __syncthreads();

            if (kc + 8 < Ee) {
                if (tid < 256) av = *(const float4*)(aptr + kc + 8);
                bv = *(const float4*)(bptr + (size_t)(kc + 8) * 1024);
            }

#pragma unroll
            for (int k = 0; k < 8; ++k) {
                float a_[8], b_[8];
                *(float4*)&a_[0] = *(const float4*)&As[k * 128 + ty2 * 8];
                *(float4*)&a_[4] = *(const float4*)&As[k * 128 + ty2 * 8 + 4];
                *(float4*)&b_[0] = *(const float4*)&Bs[k * 256 + tx2 * 4];
                *(float4*)&b_[4] = *(const float4*)&Bs[k * 256 + tx2 * 4 + 128];
#pragma unroll
                for (int i = 0; i < 8; ++i)
#pragma unroll
                    for (int j = 0; j < 8; ++j)
                        acc[i][j] = fmaf(a_[i], b_[j], acc[i][j]);
            }
            __syncthreads();
        }

        int dd = nt >> 1, ncol = (nt & 1) * 256;
        float* base = Uc + (size_t)dd * ((size_t)Tt * Bb * G4);
#pragma unroll
        for (int i = 0; i < 8; ++i) {
            float* dst = base + (size_t)(m0 + ty2 * 8 + i) * G4 + ncol + tx2 * 4;
            *(float4*)dst = make_float4(acc[i][0], acc[i][1], acc[i][2], acc[i][3]);
            *(float4*)(dst + 128) = make_float4(acc[i][4], acc[i][5],
                                                acc[i][6], acc[i][7]);
        }
        __threadfence();
        __syncthreads();
        if (tid == 0) atomicAdd(&flags[dd * 512 + mt], 1);
    }
}

// ---------------------------------------------------------------------------
// fused producer/consumer kernel. 86KB static LDS > 160KB/2 forces ONE block
// per CU (no producer/consumer CU-sharing — the round-5 2x regression).
// ---------------------------------------------------------------------------
__global__ __launch_bounds__(512) void k_fused(const int* __restrict__ sent,
                                               const float* __restrict__ emb,
                                               const float* __restrict__ Wt,
                                               float* __restrict__ Uc,
                                               const float* __restrict__ Whh_f,
                                               const float* __restrict__ Whh_b,
                                               const float* __restrict__ bih_f,
                                               const float* __restrict__ bhh_f,
                                               const float* __restrict__ bih_b,
                                               const float* __restrict__ bhh_b,
                                               const float* __restrict__ h0,
                                               const float* __restrict__ c0,
                                               const float* __restrict__ Wout,
                                               float* __restrict__ hst,
                                               float* __restrict__ cst,
                                               float* __restrict__ pf,
                                               int* __restrict__ flags) {
    __shared__ float smem[21504];      // 86016 B: CU-exclusive occupancy
    int bi = blockIdx.x;
    if (bi < 128) {
        gemm_producer(sent, emb, Wt, Uc, flags, bi, smem);
    } else {
        int cb = bi - 128;
        int d = cb >> 6, b = cb & 63;
        lstm_consumer(Uc, d ? Whh_b : Whh_f, d ? bih_b : bih_f,
                      d ? bhh_b : bhh_f, h0, c0, Wout, hst, cst, pf,
                      flags, b, d, 0, Tt, 1, 1, smem);
    }
}

// ---------------------------------------------------------------------------
// fallback (small ws): chunked gemm (256 thr) + solo lstm, sequential.
// ---------------------------------------------------------------------------
__global__ __launch_bounds__(256, 2) void k_gemm2(const int* __restrict__ sent,
                                                  const float* __restrict__ emb,
                                                  const float* __restrict__ Wt,
                                                  float* __restrict__ Uc,
                                                  int c0T, int CT) {
    __shared__ float As[8][128];
    __shared__ float Bs[8][256];
    __shared__ int   toks[128];

    int tid = threadIdx.x;
    int n0  = blockIdx.x * 256;
    int m0  = blockIdx.y * 128;
    int dz  = blockIdx.z;
    int ty  = tid >> 4, tx = tid & 15;

    if (tid < 128) {
        int m = m0 + tid;
        int it = m >> 6, b = m & 63;
        int t = dz ? (Tt - 1 - (c0T + it)) : (c0T + it);
        toks[tid] = sent[b * Tt + t];
    }
    __syncthreads();

    int am = tid & 127, ak4 = tid >> 7;
    int brow = tid >> 5, bc4 = tid & 31;

    const float* aptr = emb + (size_t)toks[am] * Ee + ak4 * 4;
    const float* bptr = Wt + (size_t)brow * 1024 + dz * G4 + n0 + bc4 * 4;

    float acc[8][16];
#pragma unroll
    for (int i = 0; i < 8; ++i)
#pragma unroll
        for (int j = 0; j < 16; ++j) acc[i][j] = 0.f;

    for (int kc = 0; kc < Ee; kc += 8) {
        float4 av  = *(const float4*)(aptr + kc);
        float4 bv0 = *(const float4*)(bptr + (size_t)kc * 1024);
        float4 bv1 = *(const float4*)(bptr + (size_t)kc * 1024 + 128);
        As[ak4 * 4 + 0][am] = av.x;
        As[ak4 * 4 + 1][am] = av.y;
        As[ak4 * 4 + 2][am] = av.z;
        As[ak4 * 4 + 3][am] = av.w;
        *(float4*)&Bs[brow][bc4 * 4]       = bv0;
        *(float4*)&Bs[brow][128 + bc4 * 4] = bv1;
        __syncthreads();
#pragma unroll
        for (int k = 0; k < 8; ++k) {
            float a_[8], b_[16];
            *(float4*)&a_[0] = *(const float4*)&As[k][ty * 8];
            *(float4*)&a_[4] = *(const float4*)&As[k][ty * 8 + 4];
#pragma unroll
            for (int q = 0; q < 4; ++q)
                *(float4*)&b_[4 * q] = *(const float4*)&Bs[k][tx * 4 + 64 * q];
#pragma unroll
            for (int i = 0; i < 8; ++i)
#pragma unroll
                for (int j = 0; j < 16; ++j)
                    acc[i][j] = fmaf(a_[i], b_[j], acc[i][j]);
        }
        __syncthreads();
    }

    float* base = Uc + (size_t)dz * ((size_t)CT * Bb * G4);
#pragma unroll
    for (int i = 0; i < 8; ++i) {
        float* dst = base + (size_t)(m0 + ty * 8 + i) * G4 + n0 + tx * 4;
#pragma unroll
        for (int q = 0; q < 4; ++q)
            *(float4*)(dst + 64 * q) = make_float4(acc[i][4 * q], acc[i][4 * q + 1],
                                                   acc[i][4 * q + 2], acc[i][4 * q + 3]);
    }
}

__global__ __launch_bounds__(512) void k_lstm_solo(const float* __restrict__ Uc,
                                                   const float* __restrict__ Whh_f,
                                                   const float* __restrict__ Whh_b,
                                                   const float* __restrict__ bih_f,
                                                   const float* __restrict__ bhh_f,
                                                   const float* __restrict__ bih_b,
                                                   const float* __restrict__ bhh_b,
                                                   const float* __restrict__ h0,
                                                   const float* __restrict__ c0,
                                                   const float* __restrict__ Wout,
                                                   float* __restrict__ hst,
                                                   float* __restrict__ cst,
                                                   float* __restrict__ pf,
                                                   int c0T, int CT, int first) {
    __shared__ float smem[5464];
    int b = blockIdx.x & 63, d = blockIdx.x >> 6;
    lstm_consumer(Uc, d ? Whh_b : Whh_f, d ? bih_b : bih_f, d ? bhh_b : bhh_f,
                  h0, c0, Wout, hst, cst, pf, nullptr, b, d,
                  c0T, CT, first, 0, smem);
}

// ---------------------------------------------------------------------------
// K3: Viterbi, tree-argmax. 1 wave per b. Lanes 0..23 = half 0 (prev 0..11),
//   lanes 24..47 = half 1 (prev 12..23). First-max tournament: strictly
//   greater replaces; ties keep the lower prev index (== jnp.argmax).
// ---------------------------------------------------------------------------
#define CMB(av, ai, bv_, bi_, ov, oi)                         \
    { bool g = (bv_) > (av); ov = g ? (bv_) : (av); oi = g ? (bi_) : (ai); }

__global__ __launch_bounds__(64) void k_viterbi(const float* __restrict__ pf,
                                                const float* __restrict__ bout,
                                                const float* __restrict__ trans,
                                                float* __restrict__ out) {
    __shared__ unsigned char bptr[Tt * Kk];
    __shared__ float tsh[Kk];
    __shared__ unsigned char path[Tt];

    int lane = threadIdx.x;
    int b    = blockIdx.x;
    int half   = (lane >= Kk) ? 1 : 0;
    int n      = half ? (lane - Kk) : lane;
    int active = (lane < 2 * Kk);

    float tr[12];
    float bo = 0.f;
    if (active) {
#pragma unroll
        for (int j = 0; j < 12; ++j) tr[j] = trans[n * Kk + half * 12 + j];
        bo = bout[n];
    }
    float v = (lane == 0) ? 0.f : NEGf;   // START=0, lives in lanes 0..23

    const float* p0 = pf + (size_t)b * Tt * Kk;
    const float* p1 = pf + (size_t)(Bb + b) * Tt * Kk;

    float pre = (lane < Kk) ? (p0[n] + p1[n]) : 0.f;

    for (int t = 0; t < Tt; ++t) {
        if (active) {
            float pren = 0.f;
            if (t + 1 < Tt && half == 0)
                pren = p0[(t + 1) * Kk + n] + p1[(t + 1) * Kk + n];

            int pb = half * 12;
            float s[12];
#pragma unroll
            for (int j = 0; j < 12; ++j) s[j] = __shfl(v, pb + j) + tr[j];

            // 12 -> 6 -> 3 -> 1 first-max tournament
            float l1v[6]; int l1i[6];
#pragma unroll
            for (int j = 0; j < 6; ++j)
                CMB(s[2 * j], 2 * j, s[2 * j + 1], 2 * j + 1, l1v[j], l1i[j]);
            float l2v[3]; int l2i[3];
#pragma unroll
            for (int j = 0; j < 3; ++j)
                CMB(l1v[2 * j], l1i[2 * j], l1v[2 * j + 1], l1i[2 * j + 1],
                    l2v[j], l2i[j]);
            float dv; int di;
            CMB(l2v[0], l2i[0], l2v[1], l2i[1], dv, di);
            float best; int bp;
            CMB(dv, di, l2v[2], l2i[2], best, bp);
            bp += pb;

            // merge halves (lower half wins ties = lower prev indices)
            float ob  = __shfl(best, n + Kk);
            int   obp = __shfl(bp,   n + Kk);
            if (half == 0) {
                if (ob > best) { best = ob; bp = obp; }
                v = best + pre + bo;
                bptr[t * Kk + n] = (unsigned char)bp;
            }
            pre = pren;
        }
    }

    if (half == 0 && lane < Kk) tsh[n] = v + trans[1 * Kk + n];   // STOP=1
    __syncthreads();

    if (lane == 0) {
        float bestv = tsh[0];
        int tag = 0;
        for (int q = 1; q < Kk; ++q)
            if (tsh[q] > bestv) { bestv = tsh[q]; tag = q; }
        out[b] = bestv;
        for (int t = Tt - 1; t >= 1; --t) {
            path[t] = (unsigned char)tag;
            tag = bptr[t * Kk + tag];
        }
        path[0] = (unsigned char)tag;
    }
    __syncthreads();

    float* otag = out + Bb + (size_t)b * Tt;
    for (int t = lane; t < Tt; t += 64) otag[t] = (float)path[t];
}

// ---------------------------------------------------------------------------
// host launcher
// ---------------------------------------------------------------------------
extern "C" void kernel_launch(void* const* d_in, const int* in_sizes, int n_in,
                              void* d_out, int out_size, void* d_ws, size_t ws_size,
                              hipStream_t stream) {
    const int*   sent  = (const int*)d_in[0];
    const float* emb   = (const float*)d_in[2];
    const float* Wih_f = (const float*)d_in[3];
    const float* Whh_f = (const float*)d_in[4];
    const float* bih_f = (const float*)d_in[5];
    const float* bhh_f = (const float*)d_in[6];
    const float* Wih_b = (const float*)d_in[7];
    const float* Whh_b = (const float*)d_in[8];
    const float* bih_b = (const float*)d_in[9];
    const float* bhh_b = (const float*)d_in[10];
    const float* h0    = (const float*)d_in[11];
    const float* c0    = (const float*)d_in[12];
    const float* Wout  = (const float*)d_in[13];
    const float* bout  = (const float*)d_in[14];
    const float* trans = (const float*)d_in[15];

    float* ws    = (float*)d_ws;
    float* Wt    = ws;
    float* pf    = Wt + 204800;
    float* hst   = pf + 3145728;
    float* cst   = hst + 16384;
    int*   flags = (int*)(cst + 16384);
    float* Uc    = cst + 16384 + 1024;

    const size_t fixedf = 204800 + 3145728 + 16384 + 16384 + 1024;
    size_t needU = (size_t)2 * Tt * Bb * G4;
    int unified = ((fixedf + needU) * 4 <= ws_size);

    k_wt<<<(Ee * 1024 + 255) / 256, 256, 0, stream>>>(Wih_f, Wih_b, Wt, flags);

    if (unified) {
        k_fused<<<256, 512, 0, stream>>>(sent, emb, Wt, Uc,
                                         Whh_f, Whh_b, bih_f, bhh_f,
                                         bih_b, bhh_b, h0, c0, Wout,
                                         hst, cst, pf, flags);
    } else {
        int CT = 64;
        const int cands[3] = {512, 256, 128};
        for (int ci = 0; ci < 3; ++ci)
            if ((fixedf + (size_t)2 * cands[ci] * Bb * G4) * 4 <= ws_size) {
                CT = cands[ci]; break;
            }
        int NC = Tt / CT;
        for (int cix = 0; cix < NC; ++cix) {
            k_gemm2<<<dim3(2, CT * 64 / 128, 2), 256, 0, stream>>>(
                sent, emb, Wt, Uc, cix * CT, CT);
            k_lstm_solo<<<128, 512, 0, stream>>>(Uc, Whh_f, Whh_b, bih_f, bhh_f,
                                                 bih_b, bhh_b, h0, c0, Wout,
                                                 hst, cst, pf, cix * CT, CT,
                                                 cix == 0);
        }
    }

    k_viterbi<<<Bb, 64, 0, stream>>>(pf, bout, trans, (float*)d_out);
}